// Round 15
// baseline (331.400 us; speedup 1.0000x reference)
//
#include <hip/hip_runtime.h>

// Problem constants (from reference)
#define NL0 300000
#define NL1 60000
#define NL2 15000
#define NL3 4000
#define NE0 960000
#define NE1 240000
#define NE2 64000
#define E_ALL (NE0 + NE1 + NE2)
#define F_IN 256
#define F_HID 128
#define F_OUT 47

// Concatenated CSR row layout
#define RBASE1 NL1
#define RBASE2 (NL1 + NL2)
#define NROWS (NL1 + NL2 + NL3)

#define NPART 16                      // 2 partitions per XCD (blockIdx&15)
#define FILL_BLOCKS ((E_ALL + 255) / 256)
#define WPREP_BLOCKS ((F_IN * F_HID) / 256)

typedef __attribute__((ext_vector_type(8))) short short8v;   // 8 bf16 (4 VGPR)
typedef __attribute__((ext_vector_type(4))) float f32x4;

// ---------------------------------------------------------------------------
__device__ inline int wave_incl_scan(int v) {
    int lane = threadIdx.x & 63;
#pragma unroll
    for (int off = 1; off < 64; off <<= 1) {
        int t = __shfl_up(v, off, 64);
        if (lane >= off) v += t;
    }
    return v;
}

__device__ inline void bf16_split(float x, unsigned short& hi, unsigned short& lo) {
    unsigned int u = __float_as_uint(x);
    hi = (unsigned short)(u >> 16);
    float fh = __uint_as_float(u & 0xffff0000u);
    float l = x - fh;
    lo = (unsigned short)(__float_as_uint(l) >> 16);
}

__device__ inline int edge_row(int i, const int* __restrict__ dst0,
                               const int* __restrict__ dst1, const int* __restrict__ dst2) {
    if (i < NE0) return dst0[i];
    if (i < NE0 + NE1) return RBASE1 + dst1[i - NE0];
    return RBASE2 + dst2[i - NE0 - NE1];
}

// ---------------------------------------------------------------------------
// CSR step 1: partitioned count + packed (row<<8 | rank).  Per-(row,part)
// counts are ~Poisson(1) (max ~12 << 255), so 8 rank bits are ample.
// ---------------------------------------------------------------------------
__global__ void count_rank(const int* __restrict__ dst0, const int* __restrict__ dst1,
                           const int* __restrict__ dst2,
                           int* __restrict__ cntp, unsigned int* __restrict__ rankpk) {
    int i = blockIdx.x * 256 + threadIdx.x;
    if (i >= E_ALL) return;
    int k = edge_row(i, dst0, dst1, dst2);
    int part = blockIdx.x & (NPART - 1);
    int r = atomicAdd(&cntp[part * NROWS + k], 1);
    rankpk[i] = ((unsigned int)k << 8) | (unsigned int)r;
}

// ---------------------------------------------------------------------------
// CSR step 2a: per-1024-chunk scan over SUMMED counts (NPART copies).
// ---------------------------------------------------------------------------
__global__ __launch_bounds__(1024) void scan_blockP(const int* __restrict__ cntp,
                                                    int* __restrict__ row_start,
                                                    int* __restrict__ blocksum) {
    __shared__ int wsum[16];
    int i = blockIdx.x * 1024 + threadIdx.x;
    int lane = threadIdx.x & 63, wid = threadIdx.x >> 6;
    int v = 0;
    if (i < NROWS) {
#pragma unroll
        for (int p = 0; p < NPART; ++p) v += cntp[p * NROWS + i];
    }
    int incl = wave_incl_scan(v);
    if (lane == 63) wsum[wid] = incl;
    __syncthreads();
    if (threadIdx.x < 16) {
        int w = wsum[threadIdx.x];
#pragma unroll
        for (int off = 1; off < 16; off <<= 1) {
            int t = __shfl_up(w, off, 64);
            if ((int)threadIdx.x >= off) w += t;
        }
        wsum[threadIdx.x] = w;
    }
    __syncthreads();
    int woff = wid ? wsum[wid - 1] : 0;
    if (i < NROWS) row_start[i] = woff + incl - v;
    if (threadIdx.x == 0) blocksum[blockIdx.x] = wsum[15];
}

// ---------------------------------------------------------------------------
// CSR step 2b: add chunk offsets (per-block wave-reduce over bs) and emit
// per-partition bases pbase[p][k] = rs[k] + sum_{q<p} cntp[q][k].
// ---------------------------------------------------------------------------
__global__ __launch_bounds__(1024) void add_offsetsP(int* __restrict__ row_start,
                                                     const int* __restrict__ bs,
                                                     const int* __restrict__ cntp,
                                                     int* __restrict__ pbase) {
    __shared__ int soff;
    if (threadIdx.x < 64) {
        int s = 0;
        for (int j = threadIdx.x; j < blockIdx.x; j += 64) s += bs[j];
#pragma unroll
        for (int o = 32; o >= 1; o >>= 1) s += __shfl_xor(s, o, 64);
        if (threadIdx.x == 0) soff = s;
    }
    __syncthreads();
    int i = blockIdx.x * 1024 + threadIdx.x;
    if (i < NROWS) {
        int v = row_start[i] + soff;
        row_start[i] = v;
        int running = v;
#pragma unroll
        for (int p = 0; p < NPART; ++p) {
            pbase[p * NROWS + i] = running;
            running += cntp[p * NROWS + i];
        }
    }
    if (i == 0) row_start[NROWS] = E_ALL;
}

// ---------------------------------------------------------------------------
// CSR step 3 (+ trailing wprep): atomic-free placement; no dst re-read
// (row+rank come packed from rankpk).
// ---------------------------------------------------------------------------
__global__ void place_all(const int* __restrict__ src0, const int* __restrict__ src1,
                          const int* __restrict__ src2,
                          const int* __restrict__ pbase,
                          const unsigned int* __restrict__ rankpk,
                          int* __restrict__ ss,
                          const float* __restrict__ W1,
                          unsigned short* __restrict__ Whi,
                          unsigned short* __restrict__ Wlo) {
    int b = blockIdx.x;
    if (b >= FILL_BLOCKS) {
        int idx = (b - FILL_BLOCKS) * 256 + threadIdx.x;
        int k = idx >> 7, c = idx & 127;
        unsigned short h, l;
        bf16_split(W1[idx], h, l);
        Whi[c * 256 + k] = h;
        Wlo[c * 256 + k] = l;
        return;
    }
    int i = b * 256 + threadIdx.x;
    if (i >= E_ALL) return;
    unsigned int pk = rankpk[i];
    int k = (int)(pk >> 8);
    int r = (int)(pk & 255u);
    int s = (i < NE0) ? src0[i] : (i < NE0 + NE1) ? src1[i - NE0] : src2[i - NE0 - NE1];
    int part = b & (NPART - 1);
    ss[pbase[part * NROWS + k] + r] = s;
}

// ---------------------------------------------------------------------------
// Layer-0 gather (F=256): frozen (near random-granule load ceiling ~5.4 TB/s).
// ---------------------------------------------------------------------------
__global__ __launch_bounds__(256) void gather256(const float* __restrict__ h,
                                                 const int* __restrict__ rs,
                                                 const int* __restrict__ ss,
                                                 unsigned short* __restrict__ mhi,
                                                 unsigned short* __restrict__ mlo) {
    int lane = threadIdx.x & 63;
    int r = blockIdx.x * 4 + (threadIdx.x >> 6);
    if (r >= NL1) return;
    int s0 = rs[r], s1 = rs[r + 1];
    int tot = s1 - s0;

    const float* hp = h + (size_t)lane * 4;
    float4 acc0 = make_float4(0.f, 0.f, 0.f, 0.f);
    float4 acc1 = make_float4(0.f, 0.f, 0.f, 0.f);
    int e = s0;
    for (; e + 7 < s1; e += 8) {
        int i0 = ss[e], i1 = ss[e + 1], i2 = ss[e + 2], i3 = ss[e + 3];
        int i4 = ss[e + 4], i5 = ss[e + 5], i6 = ss[e + 6], i7 = ss[e + 7];
        float4 v0 = *(const float4*)(hp + (size_t)i0 * F_IN);
        float4 v1 = *(const float4*)(hp + (size_t)i1 * F_IN);
        float4 v2 = *(const float4*)(hp + (size_t)i2 * F_IN);
        float4 v3 = *(const float4*)(hp + (size_t)i3 * F_IN);
        float4 v4 = *(const float4*)(hp + (size_t)i4 * F_IN);
        float4 v5 = *(const float4*)(hp + (size_t)i5 * F_IN);
        float4 v6 = *(const float4*)(hp + (size_t)i6 * F_IN);
        float4 v7 = *(const float4*)(hp + (size_t)i7 * F_IN);
        acc0.x += (v0.x + v1.x) + (v2.x + v3.x);
        acc0.y += (v0.y + v1.y) + (v2.y + v3.y);
        acc0.z += (v0.z + v1.z) + (v2.z + v3.z);
        acc0.w += (v0.w + v1.w) + (v2.w + v3.w);
        acc1.x += (v4.x + v5.x) + (v6.x + v7.x);
        acc1.y += (v4.y + v5.y) + (v6.y + v7.y);
        acc1.z += (v4.z + v5.z) + (v6.z + v7.z);
        acc1.w += (v4.w + v5.w) + (v6.w + v7.w);
    }
    for (; e + 1 < s1; e += 2) {
        int i0 = ss[e], i1 = ss[e + 1];
        float4 v0 = *(const float4*)(hp + (size_t)i0 * F_IN);
        float4 v1 = *(const float4*)(hp + (size_t)i1 * F_IN);
        acc0.x += v0.x + v1.x; acc0.y += v0.y + v1.y;
        acc0.z += v0.z + v1.z; acc0.w += v0.w + v1.w;
    }
    if (e < s1) {
        int i0 = ss[e];
        float4 v0 = *(const float4*)(hp + (size_t)i0 * F_IN);
        acc0.x += v0.x; acc0.y += v0.y; acc0.z += v0.z; acc0.w += v0.w;
    }
    float inv = (tot > 0) ? 1.0f / (float)tot : 0.0f;
    float o[4] = {(acc0.x + acc1.x) * inv, (acc0.y + acc1.y) * inv,
                  (acc0.z + acc1.z) * inv, (acc0.w + acc1.w) * inv};
    ushort4 hv, lv;
    bf16_split(o[0], hv.x, lv.x);
    bf16_split(o[1], hv.y, lv.y);
    bf16_split(o[2], hv.z, lv.z);
    bf16_split(o[3], hv.w, lv.w);
    *(ushort4*)(mhi + (size_t)r * F_IN + lane * 4) = hv;
    *(ushort4*)(mlo + (size_t)r * F_IN + lane * 4) = lv;
}

// ---------------------------------------------------------------------------
// Layer-0 MFMA linear (Markidis split, W in LDS).  1024 thr, 16 waves.
// C/D: col = lane&15, row = (lane>>4)*4 + reg   [HW-verified mapping]
// ---------------------------------------------------------------------------
__global__ __launch_bounds__(1024) void mfma_lin0(const unsigned short* __restrict__ Ahi,
                                                  const unsigned short* __restrict__ Alo,
                                                  const unsigned short* __restrict__ Whi,
                                                  const unsigned short* __restrict__ Wlo,
                                                  const float* __restrict__ bias,
                                                  float* __restrict__ out, int N) {
    __shared__ unsigned short whi[F_IN * F_HID];
    __shared__ unsigned short wlo[F_IN * F_HID];

    for (int ci = threadIdx.x; ci < (F_IN * F_HID) / 8; ci += 1024) {
        int e = ci * 8;
        int c = e >> 8;
        int swz = e ^ ((c & 7) << 3);
        *(short8v*)(whi + swz) = *(const short8v*)(Whi + e);
        *(short8v*)(wlo + swz) = *(const short8v*)(Wlo + e);
    }
    __syncthreads();

    int lane = threadIdx.x & 63;
    int wid = threadIdx.x >> 6;
    int rowbase = blockIdx.x * 256 + wid * 16;
    int r = lane & 15;
    int kg = lane >> 4;

    size_t arow = (size_t)min(rowbase + r, N - 1);
    const unsigned short* pah = Ahi + arow * F_IN + kg * 8;
    const unsigned short* pal = Alo + arow * F_IN + kg * 8;

    f32x4 acc[8];
#pragma unroll
    for (int ct = 0; ct < 8; ++ct) acc[ct] = (f32x4){0.f, 0.f, 0.f, 0.f};

#pragma unroll
    for (int ks = 0; ks < 8; ++ks) {
        short8v ah = *(const short8v*)(pah + ks * 32);
        short8v al = *(const short8v*)(pal + ks * 32);
#pragma unroll
        for (int ct = 0; ct < 8; ++ct) {
            int e = (((ct * 16 + r) << 8) + ks * 32 + kg * 8) ^ ((r & 7) << 3);
            short8v bh = *(const short8v*)(whi + e);
            short8v bl = *(const short8v*)(wlo + e);
            acc[ct] = __builtin_amdgcn_mfma_f32_16x16x32_bf16(ah, bh, acc[ct], 0, 0, 0);
            acc[ct] = __builtin_amdgcn_mfma_f32_16x16x32_bf16(ah, bl, acc[ct], 0, 0, 0);
            acc[ct] = __builtin_amdgcn_mfma_f32_16x16x32_bf16(al, bh, acc[ct], 0, 0, 0);
        }
    }

    int crow = rowbase + kg * 4;
#pragma unroll
    for (int ct = 0; ct < 8; ++ct) {
        float bb = bias[ct * 16 + r];
#pragma unroll
        for (int i = 0; i < 4; ++i) {
            int rr = crow + i;
            if (rr < N) out[(size_t)rr * F_HID + ct * 16 + r] = fmaxf(acc[ct][i] + bb, 0.f);
        }
    }
}

// ---------------------------------------------------------------------------
// Fused gather+mean+linear (layers 1 and 2), ROWS=8 per block (doubled grid
// vs round 14 -> ~7 blocks/CU for the latency-bound gather).  Gather: 2
// edges/wave, full-row float4 loads; GEMM reads W from global (L2-resident).
// FOUT=128: thread = 1 row x 4 cols (32 col-groups x 8 rows).
// ---------------------------------------------------------------------------
template <int FOUT, bool RELU>
__global__ __launch_bounds__(256) void gather_linear(const float* __restrict__ h,
                                                     const int* __restrict__ rs,
                                                     const int* __restrict__ ss,
                                                     const float* __restrict__ W,
                                                     const float* __restrict__ bias,
                                                     float* __restrict__ out,
                                                     int N, int rowbase) {
    constexpr int ROWS = 8;
    __shared__ float mr[ROWS][128];

    int lane = threadIdx.x & 63;
    int w = threadIdx.x >> 6;
    int half = lane >> 5;
    int hl = lane & 31;
    int rb = blockIdx.x * ROWS;
#pragma unroll
    for (int q = 0; q < 2; ++q) {
        int lr = w * 2 + q;
        int r = rb + lr;
        float4 acc = make_float4(0.f, 0.f, 0.f, 0.f);
        if (r < N) {
            int s0 = rs[rowbase + r], s1 = rs[rowbase + r + 1];
            const float* hp = h + (size_t)hl * 4;
            int e = s0;
            for (; e + 3 < s1; e += 4) {
                int i0 = ss[e + half], i1 = ss[e + 2 + half];
                float4 v0 = *(const float4*)(hp + (size_t)i0 * F_HID);
                float4 v1 = *(const float4*)(hp + (size_t)i1 * F_HID);
                acc.x += v0.x + v1.x; acc.y += v0.y + v1.y;
                acc.z += v0.z + v1.z; acc.w += v0.w + v1.w;
            }
            if (e + 1 < s1) {
                int i0 = ss[e + half];
                float4 v0 = *(const float4*)(hp + (size_t)i0 * F_HID);
                acc.x += v0.x; acc.y += v0.y; acc.z += v0.z; acc.w += v0.w;
                e += 2;
            }
            if (e < s1 && half == 0) {
                int i0 = ss[e];
                float4 v0 = *(const float4*)(hp + (size_t)i0 * F_HID);
                acc.x += v0.x; acc.y += v0.y; acc.z += v0.z; acc.w += v0.w;
            }
            acc.x += __shfl(acc.x, lane ^ 32);
            acc.y += __shfl(acc.y, lane ^ 32);
            acc.z += __shfl(acc.z, lane ^ 32);
            acc.w += __shfl(acc.w, lane ^ 32);
            float inv = (s1 > s0) ? 1.0f / (float)(s1 - s0) : 0.0f;
            acc.x *= inv; acc.y *= inv; acc.z *= inv; acc.w *= inv;
        }
        if (half == 0) *(float4*)&mr[lr][hl * 4] = acc;
    }
    __syncthreads();

    if constexpr (FOUT == 128) {
        int c4 = (threadIdx.x & 31) * 4;
        int r0 = threadIdx.x >> 5;             // 0..7
        float4 bb = *(const float4*)&bias[c4];
        float4 a0 = bb;
#pragma unroll 8
        for (int k = 0; k < 128; ++k) {
            float4 wv = *(const float4*)&W[k * 128 + c4];
            float m0 = mr[r0][k];
            a0.x += m0 * wv.x; a0.y += m0 * wv.y; a0.z += m0 * wv.z; a0.w += m0 * wv.w;
        }
        if (RELU) {
            a0.x = fmaxf(a0.x, 0.f); a0.y = fmaxf(a0.y, 0.f);
            a0.z = fmaxf(a0.z, 0.f); a0.w = fmaxf(a0.w, 0.f);
        }
        int ra = rb + r0;
        if (ra < N) *(float4*)&out[(size_t)ra * 128 + c4] = a0;
    } else {
        int j = lane;
        int rg = w;
        if (j < FOUT) {
            float bb = bias[j];
            float a0 = bb, a1 = bb;
#pragma unroll 8
            for (int k = 0; k < 128; ++k) {
                float wv = W[k * FOUT + j];
                a0 += mr[rg][k] * wv;
                a1 += mr[rg + 4][k] * wv;
            }
            if (RELU) { a0 = fmaxf(a0, 0.f); a1 = fmaxf(a1, 0.f); }
            int ra = rb + rg, rb2 = rb + rg + 4;
            if (ra < N) out[(size_t)ra * FOUT + j] = a0;
            if (rb2 < N) out[(size_t)rb2 * FOUT + j] = a1;
        }
    }
}

// ---------------------------------------------------------------------------

static inline size_t align256(size_t x) { return (x + 255) & ~size_t(255); }

extern "C" void kernel_launch(void* const* d_in, const int* in_sizes, int n_in,
                              void* d_out, int out_size, void* d_ws, size_t ws_size,
                              hipStream_t stream) {
    const float* features = (const float*)d_in[0];
    const int*   src0     = (const int*)d_in[1];
    const int*   dst0     = (const int*)d_in[2];
    const int*   src1     = (const int*)d_in[3];
    const int*   dst1     = (const int*)d_in[4];
    const int*   src2     = (const int*)d_in[5];
    const int*   dst2     = (const int*)d_in[6];
    const float* W1       = (const float*)d_in[7];
    const float* b1       = (const float*)d_in[8];
    const float* W2       = (const float*)d_in[9];
    const float* b2       = (const float*)d_in[10];
    const float* W3       = (const float*)d_in[11];
    const float* b3       = (const float*)d_in[12];
    float* out = (float*)d_out;

    char* p = (char*)d_ws;
    size_t off = 0;
    auto alloc = [&](size_t bytes) {
        char* r = p + off;
        off += align256(bytes);
        return r;
    };
    unsigned short* m0hi = (unsigned short*)alloc(sizeof(unsigned short) * (size_t)NL1 * F_IN);
    unsigned short* m0lo = (unsigned short*)alloc(sizeof(unsigned short) * (size_t)NL1 * F_IN);
    unsigned short* wt_hi = (unsigned short*)alloc(sizeof(unsigned short) * F_IN * F_HID);
    unsigned short* wt_lo = (unsigned short*)alloc(sizeof(unsigned short) * F_IN * F_HID);
    float* h1 = (float*)alloc(sizeof(float) * (size_t)NL1 * F_HID);
    float* h2 = (float*)alloc(sizeof(float) * (size_t)NL2 * F_HID);
    int* cntp  = (int*)alloc(sizeof(int) * NPART * NROWS);
    int* pbase = (int*)alloc(sizeof(int) * NPART * NROWS);
    unsigned int* rankpk = (unsigned int*)alloc(sizeof(unsigned int) * E_ALL);
    int* rs    = (int*)alloc(sizeof(int) * (NROWS + 1));
    int* bs    = (int*)alloc(sizeof(int) * 1024);
    int* ss    = (int*)alloc(sizeof(int) * E_ALL);
    (void)ws_size;

    // ---- 2-level XCD-partitioned CSR build (1 atomic pass, packed rank) ----
    hipMemsetAsync(cntp, 0, sizeof(int) * NPART * NROWS, stream);
    count_rank<<<FILL_BLOCKS, 256, 0, stream>>>(dst0, dst1, dst2, cntp, rankpk);
    int nb = (NROWS + 1023) / 1024;
    scan_blockP<<<nb, 1024, 0, stream>>>(cntp, rs, bs);
    add_offsetsP<<<nb, 1024, 0, stream>>>(rs, bs, cntp, pbase);
    place_all<<<FILL_BLOCKS + WPREP_BLOCKS, 256, 0, stream>>>(
        src0, src1, src2, pbase, rankpk, ss, W1, wt_hi, wt_lo);

    // ---- Layer 0 -> 1: gather (bf16 hi/lo out) + MFMA split-GEMM ----
    gather256<<<NL1 / 4, 256, 0, stream>>>(features, rs, ss, m0hi, m0lo);
    mfma_lin0<<<(NL1 + 255) / 256, 1024, 0, stream>>>(m0hi, m0lo, wt_hi, wt_lo, b1, h1, NL1);

    // ---- Layer 1 -> 2 ----
    gather_linear<128, true><<<(NL2 + 7) / 8, 256, 0, stream>>>(
        h1, rs, ss, W2, b2, h2, NL2, RBASE1);

    // ---- Layer 2 -> 3 ----
    gather_linear<F_OUT, false><<<(NL3 + 7) / 8, 256, 0, stream>>>(
        h2, rs, ss, W3, b3, out, NL3, RBASE2);
}

// Round 16
// 316.717 us; speedup vs baseline: 1.0464x; 1.0464x over previous
//
#include <hip/hip_runtime.h>

// Problem constants (from reference)
#define NL0 300000
#define NL1 60000
#define NL2 15000
#define NL3 4000
#define NE0 960000
#define NE1 240000
#define NE2 64000
#define E_ALL (NE0 + NE1 + NE2)
#define F_IN 256
#define F_HID 128
#define F_OUT 47

// Concatenated CSR row layout
#define RBASE1 NL1
#define RBASE2 (NL1 + NL2)
#define NROWS (NL1 + NL2 + NL3)

#define NPART 8                       // 1 partition per XCD (blockIdx&7)
#define FILL_BLOCKS ((E_ALL + 255) / 256)
#define WPREP_BLOCKS ((F_IN * F_HID) / 256)

typedef __attribute__((ext_vector_type(8))) short short8v;   // 8 bf16 (4 VGPR)
typedef __attribute__((ext_vector_type(4))) float f32x4;

// ---------------------------------------------------------------------------
__device__ inline int wave_incl_scan(int v) {
    int lane = threadIdx.x & 63;
#pragma unroll
    for (int off = 1; off < 64; off <<= 1) {
        int t = __shfl_up(v, off, 64);
        if (lane >= off) v += t;
    }
    return v;
}

__device__ inline void bf16_split(float x, unsigned short& hi, unsigned short& lo) {
    unsigned int u = __float_as_uint(x);
    hi = (unsigned short)(u >> 16);
    float fh = __uint_as_float(u & 0xffff0000u);
    float l = x - fh;
    lo = (unsigned short)(__float_as_uint(l) >> 16);
}

__device__ inline int edge_row(int i, const int* __restrict__ dst0,
                               const int* __restrict__ dst1, const int* __restrict__ dst2) {
    if (i < NE0) return dst0[i];
    if (i < NE0 + NE1) return RBASE1 + dst1[i - NE0];
    return RBASE2 + dst2[i - NE0 - NE1];
}

// ---------------------------------------------------------------------------
// CSR step 1: partitioned count + packed (row<<8 | rank).  Per-(row,part)
// counts are ~Poisson(2) (max ~14 << 255), so 8 rank bits are ample.
// ---------------------------------------------------------------------------
__global__ void count_rank(const int* __restrict__ dst0, const int* __restrict__ dst1,
                           const int* __restrict__ dst2,
                           int* __restrict__ cntp, unsigned int* __restrict__ rankpk) {
    int i = blockIdx.x * 256 + threadIdx.x;
    if (i >= E_ALL) return;
    int k = edge_row(i, dst0, dst1, dst2);
    int part = blockIdx.x & (NPART - 1);
    int r = atomicAdd(&cntp[part * NROWS + k], 1);
    rankpk[i] = ((unsigned int)k << 8) | (unsigned int)r;
}

// ---------------------------------------------------------------------------
// CSR step 2a: per-1024-chunk scan over SUMMED counts (NPART copies).
// ---------------------------------------------------------------------------
__global__ __launch_bounds__(1024) void scan_blockP(const int* __restrict__ cntp,
                                                    int* __restrict__ row_start,
                                                    int* __restrict__ blocksum) {
    __shared__ int wsum[16];
    int i = blockIdx.x * 1024 + threadIdx.x;
    int lane = threadIdx.x & 63, wid = threadIdx.x >> 6;
    int v = 0;
    if (i < NROWS) {
#pragma unroll
        for (int p = 0; p < NPART; ++p) v += cntp[p * NROWS + i];
    }
    int incl = wave_incl_scan(v);
    if (lane == 63) wsum[wid] = incl;
    __syncthreads();
    if (threadIdx.x < 16) {
        int w = wsum[threadIdx.x];
#pragma unroll
        for (int off = 1; off < 16; off <<= 1) {
            int t = __shfl_up(w, off, 64);
            if ((int)threadIdx.x >= off) w += t;
        }
        wsum[threadIdx.x] = w;
    }
    __syncthreads();
    int woff = wid ? wsum[wid - 1] : 0;
    if (i < NROWS) row_start[i] = woff + incl - v;
    if (threadIdx.x == 0) blocksum[blockIdx.x] = wsum[15];
}

// ---------------------------------------------------------------------------
// CSR step 2b: add chunk offsets (per-block wave-reduce over bs) and emit
// per-partition bases pbase[p][k] = rs[k] + sum_{q<p} cntp[q][k].
// ---------------------------------------------------------------------------
__global__ __launch_bounds__(1024) void add_offsetsP(int* __restrict__ row_start,
                                                     const int* __restrict__ bs,
                                                     const int* __restrict__ cntp,
                                                     int* __restrict__ pbase) {
    __shared__ int soff;
    if (threadIdx.x < 64) {
        int s = 0;
        for (int j = threadIdx.x; j < blockIdx.x; j += 64) s += bs[j];
#pragma unroll
        for (int o = 32; o >= 1; o >>= 1) s += __shfl_xor(s, o, 64);
        if (threadIdx.x == 0) soff = s;
    }
    __syncthreads();
    int i = blockIdx.x * 1024 + threadIdx.x;
    if (i < NROWS) {
        int v = row_start[i] + soff;
        row_start[i] = v;
        int running = v;
#pragma unroll
        for (int p = 0; p < NPART; ++p) {
            pbase[p * NROWS + i] = running;
            running += cntp[p * NROWS + i];
        }
    }
    if (i == 0) row_start[NROWS] = E_ALL;
}

// ---------------------------------------------------------------------------
// CSR step 3 (+ trailing wprep): atomic-free placement; no dst re-read
// (row+rank come packed from rankpk).
// ---------------------------------------------------------------------------
__global__ void place_all(const int* __restrict__ src0, const int* __restrict__ src1,
                          const int* __restrict__ src2,
                          const int* __restrict__ pbase,
                          const unsigned int* __restrict__ rankpk,
                          int* __restrict__ ss,
                          const float* __restrict__ W1,
                          unsigned short* __restrict__ Whi,
                          unsigned short* __restrict__ Wlo) {
    int b = blockIdx.x;
    if (b >= FILL_BLOCKS) {
        int idx = (b - FILL_BLOCKS) * 256 + threadIdx.x;
        int k = idx >> 7, c = idx & 127;
        unsigned short h, l;
        bf16_split(W1[idx], h, l);
        Whi[c * 256 + k] = h;
        Wlo[c * 256 + k] = l;
        return;
    }
    int i = b * 256 + threadIdx.x;
    if (i >= E_ALL) return;
    unsigned int pk = rankpk[i];
    int k = (int)(pk >> 8);
    int r = (int)(pk & 255u);
    int s = (i < NE0) ? src0[i] : (i < NE0 + NE1) ? src1[i - NE0] : src2[i - NE0 - NE1];
    int part = b & (NPART - 1);
    ss[pbase[part * NROWS + k] + r] = s;
}

// ---------------------------------------------------------------------------
// Layer-0 gather (F=256): frozen (near random-granule load ceiling ~5.4 TB/s).
// ---------------------------------------------------------------------------
__global__ __launch_bounds__(256) void gather256(const float* __restrict__ h,
                                                 const int* __restrict__ rs,
                                                 const int* __restrict__ ss,
                                                 unsigned short* __restrict__ mhi,
                                                 unsigned short* __restrict__ mlo) {
    int lane = threadIdx.x & 63;
    int r = blockIdx.x * 4 + (threadIdx.x >> 6);
    if (r >= NL1) return;
    int s0 = rs[r], s1 = rs[r + 1];
    int tot = s1 - s0;

    const float* hp = h + (size_t)lane * 4;
    float4 acc0 = make_float4(0.f, 0.f, 0.f, 0.f);
    float4 acc1 = make_float4(0.f, 0.f, 0.f, 0.f);
    int e = s0;
    for (; e + 7 < s1; e += 8) {
        int i0 = ss[e], i1 = ss[e + 1], i2 = ss[e + 2], i3 = ss[e + 3];
        int i4 = ss[e + 4], i5 = ss[e + 5], i6 = ss[e + 6], i7 = ss[e + 7];
        float4 v0 = *(const float4*)(hp + (size_t)i0 * F_IN);
        float4 v1 = *(const float4*)(hp + (size_t)i1 * F_IN);
        float4 v2 = *(const float4*)(hp + (size_t)i2 * F_IN);
        float4 v3 = *(const float4*)(hp + (size_t)i3 * F_IN);
        float4 v4 = *(const float4*)(hp + (size_t)i4 * F_IN);
        float4 v5 = *(const float4*)(hp + (size_t)i5 * F_IN);
        float4 v6 = *(const float4*)(hp + (size_t)i6 * F_IN);
        float4 v7 = *(const float4*)(hp + (size_t)i7 * F_IN);
        acc0.x += (v0.x + v1.x) + (v2.x + v3.x);
        acc0.y += (v0.y + v1.y) + (v2.y + v3.y);
        acc0.z += (v0.z + v1.z) + (v2.z + v3.z);
        acc0.w += (v0.w + v1.w) + (v2.w + v3.w);
        acc1.x += (v4.x + v5.x) + (v6.x + v7.x);
        acc1.y += (v4.y + v5.y) + (v6.y + v7.y);
        acc1.z += (v4.z + v5.z) + (v6.z + v7.z);
        acc1.w += (v4.w + v5.w) + (v6.w + v7.w);
    }
    for (; e + 1 < s1; e += 2) {
        int i0 = ss[e], i1 = ss[e + 1];
        float4 v0 = *(const float4*)(hp + (size_t)i0 * F_IN);
        float4 v1 = *(const float4*)(hp + (size_t)i1 * F_IN);
        acc0.x += v0.x + v1.x; acc0.y += v0.y + v1.y;
        acc0.z += v0.z + v1.z; acc0.w += v0.w + v1.w;
    }
    if (e < s1) {
        int i0 = ss[e];
        float4 v0 = *(const float4*)(hp + (size_t)i0 * F_IN);
        acc0.x += v0.x; acc0.y += v0.y; acc0.z += v0.z; acc0.w += v0.w;
    }
    float inv = (tot > 0) ? 1.0f / (float)tot : 0.0f;
    float o[4] = {(acc0.x + acc1.x) * inv, (acc0.y + acc1.y) * inv,
                  (acc0.z + acc1.z) * inv, (acc0.w + acc1.w) * inv};
    ushort4 hv, lv;
    bf16_split(o[0], hv.x, lv.x);
    bf16_split(o[1], hv.y, lv.y);
    bf16_split(o[2], hv.z, lv.z);
    bf16_split(o[3], hv.w, lv.w);
    *(ushort4*)(mhi + (size_t)r * F_IN + lane * 4) = hv;
    *(ushort4*)(mlo + (size_t)r * F_IN + lane * 4) = lv;
}

// ---------------------------------------------------------------------------
// Layer-0 MFMA linear (Markidis split, W in LDS).  1024 thr, 16 waves.
// C/D: col = lane&15, row = (lane>>4)*4 + reg   [HW-verified mapping]
// ---------------------------------------------------------------------------
__global__ __launch_bounds__(1024) void mfma_lin0(const unsigned short* __restrict__ Ahi,
                                                  const unsigned short* __restrict__ Alo,
                                                  const unsigned short* __restrict__ Whi,
                                                  const unsigned short* __restrict__ Wlo,
                                                  const float* __restrict__ bias,
                                                  float* __restrict__ out, int N) {
    __shared__ unsigned short whi[F_IN * F_HID];
    __shared__ unsigned short wlo[F_IN * F_HID];

    for (int ci = threadIdx.x; ci < (F_IN * F_HID) / 8; ci += 1024) {
        int e = ci * 8;
        int c = e >> 8;
        int swz = e ^ ((c & 7) << 3);
        *(short8v*)(whi + swz) = *(const short8v*)(Whi + e);
        *(short8v*)(wlo + swz) = *(const short8v*)(Wlo + e);
    }
    __syncthreads();

    int lane = threadIdx.x & 63;
    int wid = threadIdx.x >> 6;
    int rowbase = blockIdx.x * 256 + wid * 16;
    int r = lane & 15;
    int kg = lane >> 4;

    size_t arow = (size_t)min(rowbase + r, N - 1);
    const unsigned short* pah = Ahi + arow * F_IN + kg * 8;
    const unsigned short* pal = Alo + arow * F_IN + kg * 8;

    f32x4 acc[8];
#pragma unroll
    for (int ct = 0; ct < 8; ++ct) acc[ct] = (f32x4){0.f, 0.f, 0.f, 0.f};

#pragma unroll
    for (int ks = 0; ks < 8; ++ks) {
        short8v ah = *(const short8v*)(pah + ks * 32);
        short8v al = *(const short8v*)(pal + ks * 32);
#pragma unroll
        for (int ct = 0; ct < 8; ++ct) {
            int e = (((ct * 16 + r) << 8) + ks * 32 + kg * 8) ^ ((r & 7) << 3);
            short8v bh = *(const short8v*)(whi + e);
            short8v bl = *(const short8v*)(wlo + e);
            acc[ct] = __builtin_amdgcn_mfma_f32_16x16x32_bf16(ah, bh, acc[ct], 0, 0, 0);
            acc[ct] = __builtin_amdgcn_mfma_f32_16x16x32_bf16(ah, bl, acc[ct], 0, 0, 0);
            acc[ct] = __builtin_amdgcn_mfma_f32_16x16x32_bf16(al, bh, acc[ct], 0, 0, 0);
        }
    }

    int crow = rowbase + kg * 4;
#pragma unroll
    for (int ct = 0; ct < 8; ++ct) {
        float bb = bias[ct * 16 + r];
#pragma unroll
        for (int i = 0; i < 4; ++i) {
            int rr = crow + i;
            if (rr < N) out[(size_t)rr * F_HID + ct * 16 + r] = fmaxf(acc[ct][i] + bb, 0.f);
        }
    }
}

// ---------------------------------------------------------------------------
// Fused gather+mean+linear (layers 1 and 2), ROWS=16 (round-14 config).
// Gather: 2 edges/wave, full-row float4 loads; GEMM reads W from global
// (L1/L2-resident).  LDS = mr only (8 KB) -> thread-limited occupancy.
// FOUT=128: thread = 2 rows x 4 cols (W read amortized over 2 rows).
// ---------------------------------------------------------------------------
template <int FOUT, int ROWS, bool RELU>
__global__ __launch_bounds__(256) void gather_linear(const float* __restrict__ h,
                                                     const int* __restrict__ rs,
                                                     const int* __restrict__ ss,
                                                     const float* __restrict__ W,
                                                     const float* __restrict__ bias,
                                                     float* __restrict__ out,
                                                     int N, int rowbase) {
    __shared__ float mr[ROWS][128];

    int lane = threadIdx.x & 63;
    int w = threadIdx.x >> 6;
    int half = lane >> 5;
    int hl = lane & 31;
    int rb = blockIdx.x * ROWS;
    constexpr int RPW = ROWS / 4;
#pragma unroll
    for (int q = 0; q < RPW; ++q) {
        int lr = w * RPW + q;
        int r = rb + lr;
        float4 acc = make_float4(0.f, 0.f, 0.f, 0.f);
        if (r < N) {
            int s0 = rs[rowbase + r], s1 = rs[rowbase + r + 1];
            const float* hp = h + (size_t)hl * 4;
            int e = s0;
            for (; e + 3 < s1; e += 4) {
                int i0 = ss[e + half], i1 = ss[e + 2 + half];
                float4 v0 = *(const float4*)(hp + (size_t)i0 * F_HID);
                float4 v1 = *(const float4*)(hp + (size_t)i1 * F_HID);
                acc.x += v0.x + v1.x; acc.y += v0.y + v1.y;
                acc.z += v0.z + v1.z; acc.w += v0.w + v1.w;
            }
            if (e + 1 < s1) {
                int i0 = ss[e + half];
                float4 v0 = *(const float4*)(hp + (size_t)i0 * F_HID);
                acc.x += v0.x; acc.y += v0.y; acc.z += v0.z; acc.w += v0.w;
                e += 2;
            }
            if (e < s1 && half == 0) {
                int i0 = ss[e];
                float4 v0 = *(const float4*)(hp + (size_t)i0 * F_HID);
                acc.x += v0.x; acc.y += v0.y; acc.z += v0.z; acc.w += v0.w;
            }
            acc.x += __shfl(acc.x, lane ^ 32);
            acc.y += __shfl(acc.y, lane ^ 32);
            acc.z += __shfl(acc.z, lane ^ 32);
            acc.w += __shfl(acc.w, lane ^ 32);
            float inv = (s1 > s0) ? 1.0f / (float)(s1 - s0) : 0.0f;
            acc.x *= inv; acc.y *= inv; acc.z *= inv; acc.w *= inv;
        }
        if (half == 0) *(float4*)&mr[lr][hl * 4] = acc;
    }
    __syncthreads();

    if constexpr (FOUT == 128) {
        int c4 = (threadIdx.x & 31) * 4;
        int r0 = (threadIdx.x >> 5) & 7;
        float4 bb = *(const float4*)&bias[c4];
        float4 a0 = bb, a1 = bb;
#pragma unroll 8
        for (int k = 0; k < 128; ++k) {
            float4 wv = *(const float4*)&W[k * 128 + c4];
            float m0 = mr[r0][k];
            float m1 = mr[r0 + 8][k];
            a0.x += m0 * wv.x; a0.y += m0 * wv.y; a0.z += m0 * wv.z; a0.w += m0 * wv.w;
            a1.x += m1 * wv.x; a1.y += m1 * wv.y; a1.z += m1 * wv.z; a1.w += m1 * wv.w;
        }
        if (RELU) {
            a0.x = fmaxf(a0.x, 0.f); a0.y = fmaxf(a0.y, 0.f);
            a0.z = fmaxf(a0.z, 0.f); a0.w = fmaxf(a0.w, 0.f);
            a1.x = fmaxf(a1.x, 0.f); a1.y = fmaxf(a1.y, 0.f);
            a1.z = fmaxf(a1.z, 0.f); a1.w = fmaxf(a1.w, 0.f);
        }
        int ra = rb + r0, rb2 = rb + r0 + 8;
        if (ra < N) *(float4*)&out[(size_t)ra * 128 + c4] = a0;
        if (rb2 < N) *(float4*)&out[(size_t)rb2 * 128 + c4] = a1;
    } else {
        int j = lane;
        int rg = w;
        if (j < FOUT) {
            float bb = bias[j];
            float a0 = bb, a1 = bb;
#pragma unroll 8
            for (int k = 0; k < 128; ++k) {
                float wv = W[k * FOUT + j];
                a0 += mr[rg][k] * wv;
                a1 += mr[rg + 4][k] * wv;
            }
            if (RELU) { a0 = fmaxf(a0, 0.f); a1 = fmaxf(a1, 0.f); }
            int ra = rb + rg, rb2 = rb + rg + 4;
            if (ra < N) out[(size_t)ra * FOUT + j] = a0;
            if (rb2 < N) out[(size_t)rb2 * FOUT + j] = a1;
        }
    }
}

// ---------------------------------------------------------------------------

static inline size_t align256(size_t x) { return (x + 255) & ~size_t(255); }

extern "C" void kernel_launch(void* const* d_in, const int* in_sizes, int n_in,
                              void* d_out, int out_size, void* d_ws, size_t ws_size,
                              hipStream_t stream) {
    const float* features = (const float*)d_in[0];
    const int*   src0     = (const int*)d_in[1];
    const int*   dst0     = (const int*)d_in[2];
    const int*   src1     = (const int*)d_in[3];
    const int*   dst1     = (const int*)d_in[4];
    const int*   src2     = (const int*)d_in[5];
    const int*   dst2     = (const int*)d_in[6];
    const float* W1       = (const float*)d_in[7];
    const float* b1       = (const float*)d_in[8];
    const float* W2       = (const float*)d_in[9];
    const float* b2       = (const float*)d_in[10];
    const float* W3       = (const float*)d_in[11];
    const float* b3       = (const float*)d_in[12];
    float* out = (float*)d_out;

    char* p = (char*)d_ws;
    size_t off = 0;
    auto alloc = [&](size_t bytes) {
        char* r = p + off;
        off += align256(bytes);
        return r;
    };
    unsigned short* m0hi = (unsigned short*)alloc(sizeof(unsigned short) * (size_t)NL1 * F_IN);
    unsigned short* m0lo = (unsigned short*)alloc(sizeof(unsigned short) * (size_t)NL1 * F_IN);
    unsigned short* wt_hi = (unsigned short*)alloc(sizeof(unsigned short) * F_IN * F_HID);
    unsigned short* wt_lo = (unsigned short*)alloc(sizeof(unsigned short) * F_IN * F_HID);
    float* h1 = (float*)alloc(sizeof(float) * (size_t)NL1 * F_HID);
    float* h2 = (float*)alloc(sizeof(float) * (size_t)NL2 * F_HID);
    int* cntp  = (int*)alloc(sizeof(int) * NPART * NROWS);
    int* pbase = (int*)alloc(sizeof(int) * NPART * NROWS);
    unsigned int* rankpk = (unsigned int*)alloc(sizeof(unsigned int) * E_ALL);
    int* rs    = (int*)alloc(sizeof(int) * (NROWS + 1));
    int* bs    = (int*)alloc(sizeof(int) * 1024);
    int* ss    = (int*)alloc(sizeof(int) * E_ALL);
    (void)ws_size;

    // ---- 2-level XCD-partitioned CSR build (1 atomic pass, packed rank) ----
    hipMemsetAsync(cntp, 0, sizeof(int) * NPART * NROWS, stream);
    count_rank<<<FILL_BLOCKS, 256, 0, stream>>>(dst0, dst1, dst2, cntp, rankpk);
    int nb = (NROWS + 1023) / 1024;
    scan_blockP<<<nb, 1024, 0, stream>>>(cntp, rs, bs);
    add_offsetsP<<<nb, 1024, 0, stream>>>(rs, bs, cntp, pbase);
    place_all<<<FILL_BLOCKS + WPREP_BLOCKS, 256, 0, stream>>>(
        src0, src1, src2, pbase, rankpk, ss, W1, wt_hi, wt_lo);

    // ---- Layer 0 -> 1: gather (bf16 hi/lo out) + MFMA split-GEMM ----
    gather256<<<NL1 / 4, 256, 0, stream>>>(features, rs, ss, m0hi, m0lo);
    mfma_lin0<<<(NL1 + 255) / 256, 1024, 0, stream>>>(m0hi, m0lo, wt_hi, wt_lo, b1, h1, NL1);

    // ---- Layer 1 -> 2 ----
    gather_linear<128, 16, true><<<(NL2 + 15) / 16, 256, 0, stream>>>(
        h1, rs, ss, W2, b2, h2, NL2, RBASE1);

    // ---- Layer 2 -> 3 ----
    gather_linear<F_OUT, 8, false><<<(NL3 + 7) / 8, 256, 0, stream>>>(
        h2, rs, ss, W3, b3, out, NL3, RBASE2);
}